// Round 18
// baseline (243.007 us; speedup 1.0000x reference)
//
#include <hip/hip_runtime.h>
#include <hip/hip_bf16.h>
#include <stdint.h>

typedef short short8 __attribute__((ext_vector_type(8)));
typedef float f32x4 __attribute__((ext_vector_type(4)));
typedef ushort ushort4v __attribute__((ext_vector_type(4)));

#define M_Q   25088   // B*H*W = 512*49
#define M_S   3136    // NS*HS*WS = 16*196
#define IN_   12544
#define LOG2E  1.44269504f
#define SHIFT2 57.7078016f   // 40 * log2(e); exp(l-40) == exp2(l*log2e - SHIFT2)
#define NZ    8       // attention key-split (98 tiles = 2x13 + 6x12)
#define FZ    8       // fc6 K-split
#define KSTR  136     // K-LDS row stride (ushorts): 272B = 4-bank shift per row
#define PSTR  40      // P-LDS row stride (ushorts): >=32 (row length!) + pad
#define WSTR  40      // fc6 W-LDS row stride (ushorts)
#define NATT  1568    // attn blocks (196 x NZ)

__device__ __forceinline__ ushort f2bf(float f) {
  union { float f; uint32_t u; } v; v.f = f;
  uint32_t r = v.u + 0x7fffu + ((v.u >> 16) & 1u);
  return (ushort)(r >> 16);
}
// cheap round-half-up; used for P and pnum (sign-safe: mantissa round below sign bit)
__device__ __forceinline__ ushort f2bf_fast(float f) {
  union { float f; uint32_t u; } v; v.f = f;
  return (ushort)((v.u + 0x8000u) >> 16);
}
__device__ __forceinline__ float bf2f(ushort u) {
  union { uint32_t u; float f; } v; v.u = ((uint32_t)u) << 16;
  return v.f;
}
__device__ __forceinline__ f32x4 mfma16(short8 a, short8 b, f32x4 c) {
  return __builtin_amdgcn_mfma_f32_16x16x32_bf16(a, b, c, 0, 0, 0);
}

// conv weights [128,256]+[128,256] -> [256,256] bf16, plus biases (small, pre-conv)
__global__ void pack_w(const float* __restrict__ Wqv, const float* __restrict__ Wqk,
                       const float* __restrict__ bqv, const float* __restrict__ bqk,
                       const float* __restrict__ Wsv, const float* __restrict__ Wsk,
                       const float* __restrict__ bsv, const float* __restrict__ bsk,
                       ushort* __restrict__ Wq_h, float* __restrict__ biasq,
                       ushort* __restrict__ Ws_h, float* __restrict__ biass) {
  int idx = blockIdx.x * 256 + threadIdx.x;
  if (idx < 65536) {
    int n = idx >> 8;
    const float* W = (n < 128) ? (Wqv + n * 256) : (Wqk + (n - 128) * 256);
    Wq_h[idx] = f2bf(W[idx & 255]);
  } else if (idx < 131072) {
    int j = idx - 65536;
    int n = j >> 8;
    const float* W = (n < 128) ? (Wsv + n * 256) : (Wsk + (n - 128) * 256);
    Ws_h[j] = f2bf(W[j & 255]);
  } else if (idx < 131328) {
    int n = idx - 131072;
    biasq[n] = (n < 128) ? bqv[n] : bqk[n - 128];
  } else if (idx < 131584) {
    int n = idx - 131328;
    biass[n] = (n < 128) ? bsv[n] : bsk[n - 128];
  }
}

// ---------------- merged conv GEMM --------------------------------------------
// bid < 784: Q variant, n-split x2 (nh = bid/392): 64 q-rows x 128 n per block.
// bid >= 784: S variant (sb = bid-784, nb = sb/49).
__global__ __launch_bounds__(256) void gemm_conv(
    const float* __restrict__ x, const float* __restrict__ sup,
    const ushort* __restrict__ Wq_h, const ushort* __restrict__ Ws_h,
    const float* __restrict__ biasq, const float* __restrict__ biass,
    ushort* __restrict__ fuse, ushort* __restrict__ qk_h,
    ushort* __restrict__ svT, ushort* __restrict__ sk_h) {
  const int lane = threadIdx.x & 63, wv = threadIdx.x >> 6;
  const int r = lane & 15, g = lane >> 4;
  if (blockIdx.x < 784) {
    // ---- Q variant: reads x [512][256][49] f32 directly ----
    const int nh = (blockIdx.x >= 392) ? 1 : 0;
    const int bx = blockIdx.x - nh * 392;
    const int row0 = bx * 64 + wv * 16;
    const int q = row0 + r;
    const int b = q / 49, p = q - b * 49;
    const float* xb = x + (size_t)b * IN_ + p;       // + c*49
    f32x4 acc[8];
#pragma unroll
    for (int i = 0; i < 8; ++i) acc[i] = f32x4{0.f, 0.f, 0.f, 0.f};
#pragma unroll
    for (int kc = 0; kc < 8; ++kc) {
      const float* s = xb + (size_t)(kc * 32 + g * 8) * 49;
      short8 ah;
#pragma unroll
      for (int j = 0; j < 8; ++j) ah[j] = (short)f2bf(s[(size_t)j * 49]);
      const ushort* bbh = Wq_h + (size_t)(nh * 128 + r) * 256 + kc * 32 + g * 8;
#pragma unroll
      for (int nt = 0; nt < 8; ++nt) {
        short8 bh = *(const short8*)(bbh + nt * 16 * 256);
        acc[nt] = mfma16(ah, bh, acc[nt]);
      }
    }
    const int qr = row0 + g * 4;
#pragma unroll
    for (int nt = 0; nt < 8; ++nt) {
      int n = nh * 128 + nt * 16 + r;
      float bs = biasq[n];
#pragma unroll
      for (int e = 0; e < 4; ++e) {
        float v = acc[nt][e] + bs;
        int qq = qr + e;
        if (nh == 0) {
          int bb = qq / 49, pp = qq - bb * 49;
          fuse[(size_t)bb * IN_ + pp * 256 + n] = f2bf(v);
        } else {
          qk_h[(size_t)qq * 128 + (n - 128)] = f2bf(v * LOG2E);
        }
      }
    }
  } else {
    // ---- S variant: reads sup [16][256][196] f32 directly; n-split x2 ----
    const int sb = blockIdx.x - 784;
    const int nb = sb / 49;
    const int row0 = (sb - nb * 49) * 64 + wv * 16;
    const int q = row0 + r;
    const int b = q / 196, p = q - b * 196;
    const float* xb = sup + (size_t)b * 256 * 196 + p;   // + c*196
    f32x4 acc[8];
#pragma unroll
    for (int i = 0; i < 8; ++i) acc[i] = f32x4{0.f, 0.f, 0.f, 0.f};
#pragma unroll
    for (int kc = 0; kc < 8; ++kc) {
      const float* s = xb + (size_t)(kc * 32 + g * 8) * 196;
      short8 ah;
#pragma unroll
      for (int j = 0; j < 8; ++j) ah[j] = (short)f2bf(s[(size_t)j * 196]);
      const ushort* bbh = Ws_h + (size_t)(nb * 128 + r) * 256 + kc * 32 + g * 8;
#pragma unroll
      for (int nt = 0; nt < 8; ++nt) {
        short8 bh = *(const short8*)(bbh + nt * 16 * 256);
        acc[nt] = mfma16(ah, bh, acc[nt]);
      }
    }
    const int qr = row0 + g * 4;
#pragma unroll
    for (int nt = 0; nt < 8; ++nt) {
      int nl = nt * 16 + r;
      float bs = biass[nb * 128 + nl];
#pragma unroll
      for (int e = 0; e < 4; ++e) {
        float v = acc[nt][e] + bs;
        int k = qr + e;
        if (nb == 0) {
          svT[(size_t)nl * M_S + k] = f2bf(v);
        } else {
          sk_h[(size_t)k * 128 + nl] = f2bf(v);
        }
      }
    }
  }
}

// ---------------- attn + W6/W7 pack fused launch -------------------------------
#define LOAD_TILE(T)                                                            \
  do {                                                                          \
    const int kb_ = (T) * 32;                                                   \
    pkh0 = *(const short8*)(Kh + (size_t)(kb_ + row0s) * 128 + c8s * 8);        \
    pkh1 = *(const short8*)(Kh + (size_t)(kb_ + row0s + 16) * 128 + c8s * 8);   \
    pv0  = *(const short8*)(Vt + (size_t)cvs * M_S + kb_ + kc2s * 8);           \
    pv1  = *(const short8*)(Vt + (size_t)(cvs + 64) * M_S + kb_ + kc2s * 8);    \
  } while (0)
#define PUBLISH(B)                                                              \
  do {                                                                          \
    *(short8*)(&khs[B][kloff0]) = pkh0;                                         \
    *(short8*)(&khs[B][kloff1]) = pkh1;                                         \
    *(short8*)(&vvs[B][voff0]) = pv0;                                           \
    *(short8*)(&vvs[B][voff1]) = pv1;                                           \
  } while (0)

__global__ __launch_bounds__(256) void attn_pack_kernel(
    const ushort* __restrict__ Qh, const ushort* __restrict__ Kh,
    const ushort* __restrict__ Vt, ushort* __restrict__ pnum,
    float* __restrict__ pden,
    const float* __restrict__ W6c, const float* __restrict__ W6r,
    ushort* __restrict__ W6p,
    const float* __restrict__ W7c, const float* __restrict__ W7r,
    ushort* __restrict__ W7p) {
  __shared__ char smem[38912];
  const int bid = blockIdx.x;
  const int tid = threadIdx.x;

  if (bid >= NATT) {
    const int pb = bid - NATT;
    if (pb < 2048) {
      // W6 [n][c*49+p] f32 -> W6p [n][p*256+c] bf16 via LDS tile
      ushort* tile = (ushort*)smem;                    // 25088 B < 38912
      const int n = pb;
      const float* src = (n < 1024) ? (W6c + (size_t)n * IN_)
                                    : (W6r + (size_t)(n - 1024) * IN_);
      ushort* dst = W6p + (size_t)n * IN_;
#pragma unroll 7
      for (int j = 0; j < 49; ++j) {
        int i = j * 256 + tid;
        tile[i] = f2bf(src[i]);
      }
      __syncthreads();
#pragma unroll 7
      for (int j = 0; j < 49; ++j) {
        int o = j * 256 + tid;
        int c = o & 255, p = o >> 8;
        dst[o] = tile[c * 49 + p];
      }
    } else {
      int idx = (pb - 2048) * 256 + tid;               // exactly 2048*1024
      float v = (idx < 1048576) ? W7c[idx] : W7r[idx - 1048576];
      W7p[idx] = f2bf(v);
    }
    return;
  }

  // ---- attention branch ----
  ushort (*khs)[32 * KSTR]  = (ushort(*)[32 * KSTR])smem;            // 17408 B
  ushort (*vvs)[128 * 32]   = (ushort(*)[128 * 32])(smem + 17408);   // 16384 B
  ushort (*plds)[16 * PSTR] = (ushort(*)[16 * PSTR])(smem + 33792);  //  5120 B

  const int z = bid / 196;
  const int bx = bid - z * 196;
  const int w = tid >> 6, lane = tid & 63;
  const int r = lane & 15, g = lane >> 4;
  const int q0 = bx * 128 + w * 32;
  const int t0 = z * 12 + (z < 2 ? z : 2);
  const int tn = 12 + (z < 2 ? 1 : 0);
  ushort* pw = plds[w];

  const int row0s = tid >> 4, c8s = tid & 15;
  const int cvs = tid >> 2, kc2s = tid & 3;
  const int kloff0 = row0s * KSTR + c8s * 8;
  const int kloff1 = (row0s + 16) * KSTR + c8s * 8;
  const int voff0 = cvs * 32 + kc2s * 8;
  const int voff1 = (cvs + 64) * 32 + kc2s * 8;

  short8 aq[2][4];
#pragma unroll
  for (int mt = 0; mt < 2; ++mt)
#pragma unroll
    for (int kc = 0; kc < 4; ++kc)
      aq[mt][kc] = *(const short8*)(Qh + (size_t)(q0 + mt * 16 + r) * 128 + kc * 32 + g * 8);

  f32x4 acc[2][8];
#pragma unroll
  for (int mt = 0; mt < 2; ++mt)
#pragma unroll
    for (int ct = 0; ct < 8; ++ct) acc[mt][ct] = f32x4{0.f, 0.f, 0.f, 0.f};
  float den[2][4];
#pragma unroll
  for (int mt = 0; mt < 2; ++mt)
#pragma unroll
    for (int e = 0; e < 4; ++e) den[mt][e] = 0.f;

  short8 pkh0, pkh1, pv0, pv1;
  LOAD_TILE(t0);
  PUBLISH(0);
  if (tn > 1) LOAD_TILE(t0 + 1);
  __syncthreads();

  for (int i = 0; i < tn; ++i) {
    const int b = i & 1;
    if (i + 1 < tn) {
      PUBLISH(b ^ 1);                 // buf^1 last read at barrier ending i-1
      if (i + 2 < tn) LOAD_TILE(t0 + i + 2);
    }
    // ---- QK^T from LDS buf b (bf16 x bf16); prio-boost the MFMA cluster ----
    f32x4 lg[2][2];
    __builtin_amdgcn_s_setprio(1);
#pragma unroll
    for (int kt = 0; kt < 2; ++kt) {
      const int kbase = (kt * 16 + r) * KSTR;
      short8 bh[4];
#pragma unroll
      for (int kc = 0; kc < 4; ++kc)
        bh[kc] = *(const short8*)(&khs[b][kbase + (kc * 4 + g) * 8]);
#pragma unroll
      for (int mt = 0; mt < 2; ++mt) {
        f32x4 c = f32x4{0.f, 0.f, 0.f, 0.f};
#pragma unroll
        for (int kc = 0; kc < 4; ++kc)
          c = mfma16(aq[mt][kc], bh[kc], c);
        lg[mt][kt] = c;
      }
    }
    __builtin_amdgcn_s_setprio(0);
    // ---- V fragments (mt-invariant) ----
    short8 vf[8];
#pragma unroll
    for (int ct = 0; ct < 8; ++ct)
      vf[ct] = *(const short8*)(&vvs[b][(ct * 16 + r) * 32 + g * 8]);
    // ---- per-mt: exp2 -> P (per-wave LDS slice) -> PV ----
#pragma unroll
    for (int mt = 0; mt < 2; ++mt) {
#pragma unroll
      for (int kt = 0; kt < 2; ++kt)
#pragma unroll
        for (int e = 0; e < 4; ++e) {
          float p = __builtin_amdgcn_exp2f(lg[mt][kt][e] - SHIFT2);
          den[mt][e] += p;
          pw[(g * 4 + e) * PSTR + kt * 16 + r] = f2bf_fast(p);
        }
      short8 pf = *(const short8*)(pw + r * PSTR + g * 8);
      __builtin_amdgcn_s_setprio(1);
#pragma unroll
      for (int ct = 0; ct < 8; ++ct)
        acc[mt][ct] = mfma16(pf, vf[ct], acc[mt][ct]);
      __builtin_amdgcn_s_setprio(0);
    }
    __syncthreads();
  }

#pragma unroll
  for (int mt = 0; mt < 2; ++mt)
#pragma unroll
    for (int e = 0; e < 4; ++e) {
      float d = den[mt][e];
      d += __shfl_xor(d, 1);
      d += __shfl_xor(d, 2);
      d += __shfl_xor(d, 4);
      d += __shfl_xor(d, 8);
      den[mt][e] = d;
    }
#pragma unroll
  for (int mt = 0; mt < 2; ++mt)
#pragma unroll
    for (int ct = 0; ct < 8; ++ct)
#pragma unroll
      for (int e = 0; e < 4; ++e) {
        int q = q0 + mt * 16 + g * 4 + e;
        int c = ct * 16 + r;
        pnum[((size_t)z * M_Q + q) * 128 + c] = f2bf_fast(acc[mt][ct][e]);
      }
  if (r == 0) {
#pragma unroll
    for (int mt = 0; mt < 2; ++mt)
#pragma unroll
      for (int e = 0; e < 4; ++e)
        pden[(size_t)z * M_Q + q0 + mt * 16 + g * 4 + e] = den[mt][e];
  }
}

// combine key-split partials (bf16 num, f32 den) -> att half of fuse
__global__ void attn_reduce(const ushort* __restrict__ pnum, const float* __restrict__ pden,
                            ushort* __restrict__ fuse) {
  int idx = blockIdx.x * 256 + threadIdx.x;  // exactly 25088*32 (c-quads)
  int q = idx >> 5;
  int c4 = (idx & 31) * 4;
  float4 s = {0.f, 0.f, 0.f, 0.f};
  float d = 0.f;
#pragma unroll
  for (int z = 0; z < NZ; ++z) {
    ushort4v v = *(const ushort4v*)(pnum + ((size_t)z * M_Q + q) * 128 + c4);
    s.x += bf2f(v[0]); s.y += bf2f(v[1]); s.z += bf2f(v[2]); s.w += bf2f(v[3]);
    d += pden[(size_t)z * M_Q + q];
  }
  float inv = 1.0f / d;
  int b = q / 49, p = q - b * 49;
  ushort4v o;
  o[0] = f2bf(s.x * inv); o[1] = f2bf(s.y * inv);
  o[2] = f2bf(s.z * inv); o[3] = f2bf(s.w * inv);
  *(ushort4v*)(fuse + (size_t)b * IN_ + p * 256 + 128 + c4) = o;
}

// ---------------- fc6: 512-thread blocks (8 waves), K-split FZ=8 ---------------
__global__ __launch_bounds__(512) void fc6_kernel(
    const ushort* __restrict__ fuse, const ushort* __restrict__ W6p,
    float* __restrict__ part) {
  __shared__ ushort wlds[2][64 * WSTR];
  const int lane = threadIdx.x & 63, wv = threadIdx.x >> 6;
  const int r = lane & 15, g = lane >> 4;
  const int m0 = wv * 64;
  const int kz = blockIdx.x & 7;
  const int nidx = (blockIdx.x >> 3) + 4 * blockIdx.y;   // [0,32)
  const int n0 = nidx * 64;
  const int k0 = kz * 1568;

  const int srow = threadIdx.x >> 2;          // 0..127 (only <64 used)
  const int skc  = (threadIdx.x & 3) * 8;     // 0,8,16,24
  const bool stager = (threadIdx.x < 256);
  const size_t wgbase = (size_t)(n0 + (srow & 63)) * IN_ + k0 + skc;
  const int wloff = (srow & 63) * WSTR + skc;

  f32x4 acc[4][4];
#pragma unroll
  for (int mt = 0; mt < 4; ++mt)
#pragma unroll
    for (int nt = 0; nt < 4; ++nt) acc[mt][nt] = f32x4{0.f, 0.f, 0.f, 0.f};

  short8 rA, rB;
  if (stager) {
    rA = *(const short8*)(W6p + wgbase);                 // slab 0
    *(short8*)(&wlds[0][wloff]) = rA;
    rA = *(const short8*)(W6p + wgbase + 32);            // slab 1
    rB = *(const short8*)(W6p + wgbase + 64);            // slab 2
  }
  __syncthreads();

  for (int t = 0; t < 49; ++t) {
    const int b = t & 1;
    if (t + 1 < 49 && stager) {
      *(short8*)(&wlds[b ^ 1][wloff]) = rA;              // publish slab t+1
      rA = rB;
      if (t + 3 < 49) rB = *(const short8*)(W6p + wgbase + (size_t)(t + 3) * 32);
    }
    const int kcol = k0 + t * 32 + g * 8;
    short8 af[4];
#pragma unroll
    for (int mt = 0; mt < 4; ++mt)
      af[mt] = *(const short8*)(fuse + (size_t)(m0 + mt * 16 + r) * IN_ + kcol);
    short8 bfr[4];
#pragma unroll
    for (int nt = 0; nt < 4; ++nt)
      bfr[nt] = *(const short8*)(&wlds[b][(nt * 16 + r) * WSTR + g * 8]);
#pragma unroll
    for (int mt = 0; mt < 4; ++mt)
#pragma unroll
      for (int nt = 0; nt < 4; ++nt) acc[mt][nt] = mfma16(af[mt], bfr[nt], acc[mt][nt]);
    __syncthreads();
  }
#pragma unroll
  for (int mt = 0; mt < 4; ++mt)
#pragma unroll
    for (int nt = 0; nt < 4; ++nt)
#pragma unroll
      for (int e = 0; e < 4; ++e) {
        int m = m0 + mt * 16 + g * 4 + e;
        int n = n0 + nt * 16 + r;
        part[(size_t)kz * 1048576 + (size_t)m * 2048 + n] = acc[mt][nt][e];
      }
}

// sum split-K partials + bias + relu -> X7 bf16 [512][2048]; float4 IO
__global__ void fc6_reduce(const float* __restrict__ part, const float* __restrict__ b6c,
                           const float* __restrict__ b6r, ushort* __restrict__ X7) {
  int idx4 = (blockIdx.x * 256 + threadIdx.x) * 4;  // grid 1024 -> 1,048,576 elems
  float4 s = {0.f, 0.f, 0.f, 0.f};
#pragma unroll
  for (int z = 0; z < FZ; ++z) {
    float4 v = *(const float4*)(part + (size_t)z * 1048576 + idx4);
    s.x += v.x; s.y += v.y; s.z += v.z; s.w += v.w;
  }
  int n = idx4 & 2047;   // 4-aligned; halves split at 1024 (4-aligned) -> no straddle
  const float* bb = (n < 1024) ? (b6c + n) : (b6r + (n - 1024));
  ushort4v o;
  o[0] = f2bf(fmaxf(s.x + bb[0], 0.f));
  o[1] = f2bf(fmaxf(s.y + bb[1], 0.f));
  o[2] = f2bf(fmaxf(s.z + bb[2], 0.f));
  o[3] = f2bf(fmaxf(s.w + bb[3], 0.f));
  *(ushort4v*)(X7 + idx4) = o;
}

// ---------------- fc7: [512][1024] x W7p[2048][1024]^T bf16 per half ------------
__global__ __launch_bounds__(128) void fc7_kernel(
    const ushort* __restrict__ X7, const ushort* __restrict__ W7p,
    const float* __restrict__ b7c, const float* __restrict__ b7r,
    float* __restrict__ out) {
  const int lane = threadIdx.x & 63, wv = threadIdx.x >> 6;
  const int r = lane & 15, g = lane >> 4;
  const int m0 = blockIdx.x * 32 + wv * 16;
  const int n0 = blockIdx.y * 32;
  const int half = (n0 >= 1024) ? 1 : 0;
  const int nn0 = n0 - half * 1024;
  const float* b7 = half ? b7r : b7c;
  f32x4 acc[2];
#pragma unroll
  for (int nt = 0; nt < 2; ++nt) acc[nt] = f32x4{0.f, 0.f, 0.f, 0.f};
  const ushort* arow = X7 + (size_t)(m0 + r) * 2048 + half * 1024;
  for (int kk = 0; kk < 1024; kk += 32) {
    short8 a = *(const short8*)(arow + kk + g * 8);
#pragma unroll
    for (int nt = 0; nt < 2; ++nt) {
      short8 bb = *(const short8*)(W7p + (size_t)(half * 1024 + nn0 + nt * 16 + r) * 1024 + kk + g * 8);
      acc[nt] = mfma16(a, bb, acc[nt]);
    }
  }
  float* obase = out + (size_t)half * 524288;
#pragma unroll
  for (int nt = 0; nt < 2; ++nt) {
#pragma unroll
    for (int e = 0; e < 4; ++e) {
      int m = m0 + g * 4 + e;
      int n = nn0 + nt * 16 + r;
      obase[(size_t)m * 1024 + n] = fmaxf(acc[nt][e] + b7[n], 0.f);
    }
  }
}

// ---------------- launch ----------------
extern "C" void kernel_launch(void* const* d_in, const int* in_sizes, int n_in,
                              void* d_out, int out_size, void* d_ws, size_t ws_size,
                              hipStream_t stream) {
  const float* x    = (const float*)d_in[0];
  const float* sup  = (const float*)d_in[1];
  const float* Wqv  = (const float*)d_in[2];
  const float* bqv  = (const float*)d_in[3];
  const float* Wqk  = (const float*)d_in[4];
  const float* bqk  = (const float*)d_in[5];
  const float* Wsv  = (const float*)d_in[6];
  const float* bsv  = (const float*)d_in[7];
  const float* Wsk  = (const float*)d_in[8];
  const float* bsk  = (const float*)d_in[9];
  const float* W6c  = (const float*)d_in[10];
  const float* b6c  = (const float*)d_in[11];
  const float* W7c  = (const float*)d_in[12];
  const float* b7c  = (const float*)d_in[13];
  const float* W6r  = (const float*)d_in[14];
  const float* b6r  = (const float*)d_in[15];
  const float* W7r  = (const float*)d_in[16];
  const float* b7r  = (const float*)d_in[17];
  float* out = (float*)d_out;

  char* base = (char*)d_ws;
  size_t off = 0;
  auto alloc = [&](size_t bytes) {
    char* p = base + off;
    off += (bytes + 255) & ~(size_t)255;
    return p;
  };
  // Region B: attn pnum bf16 NZ=8 (51.4MB) then fc6 part f32 (33.6MB), aliased
  char* regionB = alloc((size_t)NZ * M_Q * 128 * 2);
  ushort* pnum = (ushort*)regionB;
  float*  part = (float*)regionB;
  // Persistent
  ushort* W6p  = (ushort*)alloc((size_t)2048 * IN_ * 2);
  ushort* W7p  = (ushort*)alloc((size_t)2048 * 1024 * 2);
  ushort* Wq_h = (ushort*)alloc(65536 * 2);
  ushort* Ws_h = (ushort*)alloc(65536 * 2);
  float*  biasq = (float*)alloc(256 * 4);
  float*  biass = (float*)alloc(256 * 4);
  ushort* fuse = (ushort*)alloc((size_t)512 * IN_ * 2);
  ushort* qk_h = (ushort*)alloc((size_t)M_Q * 128 * 2);
  ushort* sk_h = (ushort*)alloc((size_t)M_S * 128 * 2);
  ushort* svT  = (ushort*)alloc((size_t)M_S * 128 * 2);
  float*  pden = (float*)alloc((size_t)NZ * M_Q * 4);
  ushort* X7   = (ushort*)alloc((size_t)512 * 2048 * 2);
  if (off > ws_size) return;  // insufficient scratch; validation will show poison

  // 1) conv weight pack (small)
  pack_w<<<dim3(515), dim3(256), 0, stream>>>(Wqv, Wqk, bqv, bqk, Wsv, Wsk, bsv, bsk,
                                              Wq_h, biasq, Ws_h, biass);
  // 2) merged 1x1 convs (x/sup f32 direct), Q n-split x2 for occupancy
  gemm_conv<<<dim3(882), dim3(256), 0, stream>>>(x, sup, Wq_h, Ws_h, biasq, biass,
                                                 fuse, qk_h, svT, sk_h);
  // 3) fused attention + W6/W7 packs in one launch (packs fill CUs as attn drains)
  attn_pack_kernel<<<dim3(NATT + 2048 + 8192), dim3(256), 0, stream>>>(
      qk_h, sk_h, svT, pnum, pden, W6c, W6r, W6p, W7c, W7r, W7p);
  attn_reduce<<<dim3(3136), dim3(256), 0, stream>>>(pnum, pden, fuse);
  // 4) fc6 (512-thr blocks, K-split, XCD-local kz, W6p LDS-staged) + reduce+relu
  fc6_kernel<<<dim3(32, FZ), dim3(512), 0, stream>>>(fuse, W6p, part);
  fc6_reduce<<<dim3(1024), dim3(256), 0, stream>>>(part, b6c, b6r, X7);
  // 5) fc7 + bias + relu -> d_out (xc then xr)
  fc7_kernel<<<dim3(16, 64), dim3(128), 0, stream>>>(X7, W7p, b7c, b7r, out);
}

// Round 19
// 234.682 us; speedup vs baseline: 1.0355x; 1.0355x over previous
//
#include <hip/hip_runtime.h>
#include <hip/hip_bf16.h>
#include <stdint.h>

typedef short short8 __attribute__((ext_vector_type(8)));
typedef float f32x4 __attribute__((ext_vector_type(4)));
typedef ushort ushort4v __attribute__((ext_vector_type(4)));

#define M_Q   25088   // B*H*W = 512*49
#define M_S   3136    // NS*HS*WS = 16*196
#define IN_   12544
#define LOG2E  1.44269504f
#define SHIFT2 57.7078016f   // 40 * log2(e); exp(l-40) == exp2(l*log2e - SHIFT2)
#define NZ    8       // attention key-split (98 tiles = 2x13 + 6x12)
#define FZ    8       // fc6 K-split
#define KSTR  136     // K-LDS row stride (ushorts): 272B = 4-bank shift per row
#define PSTR  40      // P-LDS row stride (ushorts): >=32 (row length!) + pad
#define WSTR  40      // fc6 W-LDS row stride (ushorts)
#define NCONV 882     // conv blocks (784 Q n-split + 98 S)

__device__ __forceinline__ ushort f2bf(float f) {
  union { float f; uint32_t u; } v; v.f = f;
  uint32_t r = v.u + 0x7fffu + ((v.u >> 16) & 1u);
  return (ushort)(r >> 16);
}
// cheap round-half-up; used for P and pnum
__device__ __forceinline__ ushort f2bf_fast(float f) {
  union { float f; uint32_t u; } v; v.f = f;
  return (ushort)((v.u + 0x8000u) >> 16);
}
__device__ __forceinline__ float bf2f(ushort u) {
  union { uint32_t u; float f; } v; v.u = ((uint32_t)u) << 16;
  return v.f;
}
__device__ __forceinline__ f32x4 mfma16(short8 a, short8 b, f32x4 c) {
  return __builtin_amdgcn_mfma_f32_16x16x32_bf16(a, b, c, 0, 0, 0);
}

// conv weights [128,256]+[128,256] -> [256,256] bf16, plus biases (small, pre-conv)
__global__ void pack_w(const float* __restrict__ Wqv, const float* __restrict__ Wqk,
                       const float* __restrict__ bqv, const float* __restrict__ bqk,
                       const float* __restrict__ Wsv, const float* __restrict__ Wsk,
                       const float* __restrict__ bsv, const float* __restrict__ bsk,
                       ushort* __restrict__ Wq_h, float* __restrict__ biasq,
                       ushort* __restrict__ Ws_h, float* __restrict__ biass) {
  int idx = blockIdx.x * 256 + threadIdx.x;
  if (idx < 65536) {
    int n = idx >> 8;
    const float* W = (n < 128) ? (Wqv + n * 256) : (Wqk + (n - 128) * 256);
    Wq_h[idx] = f2bf(W[idx & 255]);
  } else if (idx < 131072) {
    int j = idx - 65536;
    int n = j >> 8;
    const float* W = (n < 128) ? (Wsv + n * 256) : (Wsk + (n - 128) * 256);
    Ws_h[j] = f2bf(W[j & 255]);
  } else if (idx < 131328) {
    int n = idx - 131072;
    biasq[n] = (n < 128) ? bqv[n] : bqk[n - 128];
  } else if (idx < 131584) {
    int n = idx - 131328;
    biass[n] = (n < 128) ? bsv[n] : bsk[n - 128];
  }
}

// ---------------- conv GEMMs + W6/W7 packs fused launch -------------------------
// bid < 784: Q variant (n-split x2); [784, 882): S variant;
// [882, 2930): W6 repack; [2930, 11122): W7 cvt.
// Packs (pure HBM) overlap with MFMA-bound convs.
__global__ __launch_bounds__(256) void conv_pack_kernel(
    const float* __restrict__ x, const float* __restrict__ sup,
    const ushort* __restrict__ Wq_h, const ushort* __restrict__ Ws_h,
    const float* __restrict__ biasq, const float* __restrict__ biass,
    ushort* __restrict__ fuse, ushort* __restrict__ qk_h,
    ushort* __restrict__ svT, ushort* __restrict__ sk_h,
    const float* __restrict__ W6c, const float* __restrict__ W6r,
    ushort* __restrict__ W6p,
    const float* __restrict__ W7c, const float* __restrict__ W7r,
    ushort* __restrict__ W7p) {
  __shared__ ushort tile[IN_];
  const int lane = threadIdx.x & 63, wv = threadIdx.x >> 6;
  const int r = lane & 15, g = lane >> 4;
  const int bid = blockIdx.x;
  if (bid >= NCONV) {
    const int pb = bid - NCONV;
    if (pb < 2048) {
      // W6 [n][c*49+p] f32 -> W6p [n][p*256+c] bf16 via LDS tile
      const int n = pb;
      const float* src = (n < 1024) ? (W6c + (size_t)n * IN_)
                                    : (W6r + (size_t)(n - 1024) * IN_);
      ushort* dst = W6p + (size_t)n * IN_;
#pragma unroll 7
      for (int j = 0; j < 49; ++j) {
        int i = j * 256 + threadIdx.x;
        tile[i] = f2bf(src[i]);
      }
      __syncthreads();
#pragma unroll 7
      for (int j = 0; j < 49; ++j) {
        int o = j * 256 + threadIdx.x;
        int c = o & 255, p = o >> 8;
        dst[o] = tile[c * 49 + p];
      }
    } else {
      int idx = (pb - 2048) * 256 + threadIdx.x;   // exactly 2048*1024
      float v = (idx < 1048576) ? W7c[idx] : W7r[idx - 1048576];
      W7p[idx] = f2bf(v);
    }
    return;
  }
  if (bid < 784) {
    // ---- Q variant: reads x [512][256][49] f32 directly ----
    const int nh = (bid >= 392) ? 1 : 0;
    const int bx = bid - nh * 392;
    const int row0 = bx * 64 + wv * 16;
    const int q = row0 + r;
    const int b = q / 49, p = q - b * 49;
    const float* xb = x + (size_t)b * IN_ + p;       // + c*49
    f32x4 acc[8];
#pragma unroll
    for (int i = 0; i < 8; ++i) acc[i] = f32x4{0.f, 0.f, 0.f, 0.f};
#pragma unroll
    for (int kc = 0; kc < 8; ++kc) {
      const float* s = xb + (size_t)(kc * 32 + g * 8) * 49;
      short8 ah;
#pragma unroll
      for (int j = 0; j < 8; ++j) ah[j] = (short)f2bf(s[(size_t)j * 49]);
      const ushort* bbh = Wq_h + (size_t)(nh * 128 + r) * 256 + kc * 32 + g * 8;
#pragma unroll
      for (int nt = 0; nt < 8; ++nt) {
        short8 bh = *(const short8*)(bbh + nt * 16 * 256);
        acc[nt] = mfma16(ah, bh, acc[nt]);
      }
    }
    const int qr = row0 + g * 4;
#pragma unroll
    for (int nt = 0; nt < 8; ++nt) {
      int n = nh * 128 + nt * 16 + r;
      float bs = biasq[n];
#pragma unroll
      for (int e = 0; e < 4; ++e) {
        float v = acc[nt][e] + bs;
        int qq = qr + e;
        if (nh == 0) {
          int bb = qq / 49, pp = qq - bb * 49;
          fuse[(size_t)bb * IN_ + pp * 256 + n] = f2bf(v);
        } else {
          qk_h[(size_t)qq * 128 + (n - 128)] = f2bf(v * LOG2E);
        }
      }
    }
  } else {
    // ---- S variant: reads sup [16][256][196] f32 directly; n-split x2 ----
    const int sb = bid - 784;
    const int nb = sb / 49;
    const int row0 = (sb - nb * 49) * 64 + wv * 16;
    const int q = row0 + r;
    const int b = q / 196, p = q - b * 196;
    const float* xb = sup + (size_t)b * 256 * 196 + p;   // + c*196
    f32x4 acc[8];
#pragma unroll
    for (int i = 0; i < 8; ++i) acc[i] = f32x4{0.f, 0.f, 0.f, 0.f};
#pragma unroll
    for (int kc = 0; kc < 8; ++kc) {
      const float* s = xb + (size_t)(kc * 32 + g * 8) * 196;
      short8 ah;
#pragma unroll
      for (int j = 0; j < 8; ++j) ah[j] = (short)f2bf(s[(size_t)j * 196]);
      const ushort* bbh = Ws_h + (size_t)(nb * 128 + r) * 256 + kc * 32 + g * 8;
#pragma unroll
      for (int nt = 0; nt < 8; ++nt) {
        short8 bh = *(const short8*)(bbh + nt * 16 * 256);
        acc[nt] = mfma16(ah, bh, acc[nt]);
      }
    }
    const int qr = row0 + g * 4;
#pragma unroll
    for (int nt = 0; nt < 8; ++nt) {
      int nl = nt * 16 + r;
      float bs = biass[nb * 128 + nl];
#pragma unroll
      for (int e = 0; e < 4; ++e) {
        float v = acc[nt][e] + bs;
        int k = qr + e;
        if (nb == 0) {
          svT[(size_t)nl * M_S + k] = f2bf(v);
        } else {
          sk_h[(size_t)k * 128 + nl] = f2bf(v);
        }
      }
    }
  }
}

// ---------------- fused attention: dbuf LDS, 32 q-rows/wave, NZ=8 --------------
#define LOAD_TILE(T)                                                            \
  do {                                                                          \
    const int kb_ = (T) * 32;                                                   \
    pkh0 = *(const short8*)(Kh + (size_t)(kb_ + row0s) * 128 + c8s * 8);        \
    pkh1 = *(const short8*)(Kh + (size_t)(kb_ + row0s + 16) * 128 + c8s * 8);   \
    pv0  = *(const short8*)(Vt + (size_t)cvs * M_S + kb_ + kc2s * 8);           \
    pv1  = *(const short8*)(Vt + (size_t)(cvs + 64) * M_S + kb_ + kc2s * 8);    \
  } while (0)
#define PUBLISH(B)                                                              \
  do {                                                                          \
    *(short8*)(&khs[B][kloff0]) = pkh0;                                         \
    *(short8*)(&khs[B][kloff1]) = pkh1;                                         \
    *(short8*)(&vvs[B][voff0]) = pv0;                                           \
    *(short8*)(&vvs[B][voff1]) = pv1;                                           \
  } while (0)

__global__ __launch_bounds__(256) void attn_kernel(
    const ushort* __restrict__ Qh, const ushort* __restrict__ Kh,
    const ushort* __restrict__ Vt, ushort* __restrict__ pnum,
    float* __restrict__ pden) {
  __shared__ ushort khs[2][32 * KSTR];
  __shared__ ushort vvs[2][128 * 32];
  __shared__ ushort plds[4][16 * PSTR];
  const int tid = threadIdx.x;
  const int w = tid >> 6, lane = tid & 63;
  const int r = lane & 15, g = lane >> 4;
  const int q0 = blockIdx.x * 128 + w * 32;
  const int z = blockIdx.y;
  const int t0 = z * 12 + (z < 2 ? z : 2);
  const int tn = 12 + (z < 2 ? 1 : 0);
  ushort* pw = plds[w];

  const int row0s = tid >> 4, c8s = tid & 15;
  const int cvs = tid >> 2, kc2s = tid & 3;
  const int kloff0 = row0s * KSTR + c8s * 8;
  const int kloff1 = (row0s + 16) * KSTR + c8s * 8;
  const int voff0 = cvs * 32 + kc2s * 8;
  const int voff1 = (cvs + 64) * 32 + kc2s * 8;

  short8 aq[2][4];
#pragma unroll
  for (int mt = 0; mt < 2; ++mt)
#pragma unroll
    for (int kc = 0; kc < 4; ++kc)
      aq[mt][kc] = *(const short8*)(Qh + (size_t)(q0 + mt * 16 + r) * 128 + kc * 32 + g * 8);

  f32x4 acc[2][8];
#pragma unroll
  for (int mt = 0; mt < 2; ++mt)
#pragma unroll
    for (int ct = 0; ct < 8; ++ct) acc[mt][ct] = f32x4{0.f, 0.f, 0.f, 0.f};
  float den[2][4];
#pragma unroll
  for (int mt = 0; mt < 2; ++mt)
#pragma unroll
    for (int e = 0; e < 4; ++e) den[mt][e] = 0.f;

  short8 pkh0, pkh1, pv0, pv1;
  LOAD_TILE(t0);
  PUBLISH(0);
  if (tn > 1) LOAD_TILE(t0 + 1);
  __syncthreads();

  for (int i = 0; i < tn; ++i) {
    const int b = i & 1;
    if (i + 1 < tn) {
      PUBLISH(b ^ 1);                 // buf^1 last read at barrier ending i-1
      if (i + 2 < tn) LOAD_TILE(t0 + i + 2);
    }
    // ---- QK^T from LDS buf b (bf16 x bf16); prio-boost the MFMA cluster ----
    f32x4 lg[2][2];
    __builtin_amdgcn_s_setprio(1);
#pragma unroll
    for (int kt = 0; kt < 2; ++kt) {
      const int kbase = (kt * 16 + r) * KSTR;
      short8 bh[4];
#pragma unroll
      for (int kc = 0; kc < 4; ++kc)
        bh[kc] = *(const short8*)(&khs[b][kbase + (kc * 4 + g) * 8]);
#pragma unroll
      for (int mt = 0; mt < 2; ++mt) {
        f32x4 c = f32x4{0.f, 0.f, 0.f, 0.f};
#pragma unroll
        for (int kc = 0; kc < 4; ++kc)
          c = mfma16(aq[mt][kc], bh[kc], c);
        lg[mt][kt] = c;
      }
    }
    __builtin_amdgcn_s_setprio(0);
    // ---- V fragments (mt-invariant) ----
    short8 vf[8];
#pragma unroll
    for (int ct = 0; ct < 8; ++ct)
      vf[ct] = *(const short8*)(&vvs[b][(ct * 16 + r) * 32 + g * 8]);
    // ---- per-mt: exp2 -> P (per-wave LDS slice) -> PV ----
#pragma unroll
    for (int mt = 0; mt < 2; ++mt) {
#pragma unroll
      for (int kt = 0; kt < 2; ++kt)
#pragma unroll
        for (int e = 0; e < 4; ++e) {
          float p = __builtin_amdgcn_exp2f(lg[mt][kt][e] - SHIFT2);
          den[mt][e] += p;
          pw[(g * 4 + e) * PSTR + kt * 16 + r] = f2bf_fast(p);
        }
      short8 pf = *(const short8*)(pw + r * PSTR + g * 8);
      __builtin_amdgcn_s_setprio(1);
#pragma unroll
      for (int ct = 0; ct < 8; ++ct)
        acc[mt][ct] = mfma16(pf, vf[ct], acc[mt][ct]);
      __builtin_amdgcn_s_setprio(0);
    }
    __syncthreads();
  }

#pragma unroll
  for (int mt = 0; mt < 2; ++mt)
#pragma unroll
    for (int e = 0; e < 4; ++e) {
      float d = den[mt][e];
      d += __shfl_xor(d, 1);
      d += __shfl_xor(d, 2);
      d += __shfl_xor(d, 4);
      d += __shfl_xor(d, 8);
      den[mt][e] = d;
    }
#pragma unroll
  for (int mt = 0; mt < 2; ++mt)
#pragma unroll
    for (int ct = 0; ct < 8; ++ct)
#pragma unroll
      for (int e = 0; e < 4; ++e) {
        int q = q0 + mt * 16 + g * 4 + e;
        int c = ct * 16 + r;
        pnum[((size_t)z * M_Q + q) * 128 + c] = f2bf_fast(acc[mt][ct][e]);
      }
  if (r == 0) {
#pragma unroll
    for (int mt = 0; mt < 2; ++mt)
#pragma unroll
      for (int e = 0; e < 4; ++e)
        pden[(size_t)z * M_Q + q0 + mt * 16 + g * 4 + e] = den[mt][e];
  }
}

// combine key-split partials (bf16 num, f32 den) -> att half of fuse
__global__ void attn_reduce(const ushort* __restrict__ pnum, const float* __restrict__ pden,
                            ushort* __restrict__ fuse) {
  int idx = blockIdx.x * 256 + threadIdx.x;  // exactly 25088*32 (c-quads)
  int q = idx >> 5;
  int c4 = (idx & 31) * 4;
  float4 s = {0.f, 0.f, 0.f, 0.f};
  float d = 0.f;
#pragma unroll
  for (int z = 0; z < NZ; ++z) {
    ushort4v v = *(const ushort4v*)(pnum + ((size_t)z * M_Q + q) * 128 + c4);
    s.x += bf2f(v[0]); s.y += bf2f(v[1]); s.z += bf2f(v[2]); s.w += bf2f(v[3]);
    d += pden[(size_t)z * M_Q + q];
  }
  float inv = 1.0f / d;
  int b = q / 49, p = q - b * 49;
  ushort4v o;
  o[0] = f2bf(s.x * inv); o[1] = f2bf(s.y * inv);
  o[2] = f2bf(s.z * inv); o[3] = f2bf(s.w * inv);
  *(ushort4v*)(fuse + (size_t)b * IN_ + p * 256 + 128 + c4) = o;
}

// ---------------- fc6: 512-thread blocks (8 waves), K-split FZ=8 ---------------
__global__ __launch_bounds__(512) void fc6_kernel(
    const ushort* __restrict__ fuse, const ushort* __restrict__ W6p,
    float* __restrict__ part) {
  __shared__ ushort wlds[2][64 * WSTR];
  const int lane = threadIdx.x & 63, wv = threadIdx.x >> 6;
  const int r = lane & 15, g = lane >> 4;
  const int m0 = wv * 64;
  const int kz = blockIdx.x & 7;
  const int nidx = (blockIdx.x >> 3) + 4 * blockIdx.y;   // [0,32)
  const int n0 = nidx * 64;
  const int k0 = kz * 1568;

  const int srow = threadIdx.x >> 2;          // 0..127 (only <64 used)
  const int skc  = (threadIdx.x & 3) * 8;     // 0,8,16,24
  const bool stager = (threadIdx.x < 256);
  const size_t wgbase = (size_t)(n0 + (srow & 63)) * IN_ + k0 + skc;
  const int wloff = (srow & 63) * WSTR + skc;

  f32x4 acc[4][4];
#pragma unroll
  for (int mt = 0; mt < 4; ++mt)
#pragma unroll
    for (int nt = 0; nt < 4; ++nt) acc[mt][nt] = f32x4{0.f, 0.f, 0.f, 0.f};

  short8 rA, rB;
  if (stager) {
    rA = *(const short8*)(W6p + wgbase);                 // slab 0
    *(short8*)(&wlds[0][wloff]) = rA;
    rA = *(const short8*)(W6p + wgbase + 32);            // slab 1
    rB = *(const short8*)(W6p + wgbase + 64);            // slab 2
  }
  __syncthreads();

  for (int t = 0; t < 49; ++t) {
    const int b = t & 1;
    if (t + 1 < 49 && stager) {
      *(short8*)(&wlds[b ^ 1][wloff]) = rA;              // publish slab t+1
      rA = rB;
      if (t + 3 < 49) rB = *(const short8*)(W6p + wgbase + (size_t)(t + 3) * 32);
    }
    const int kcol = k0 + t * 32 + g * 8;
    short8 af[4];
#pragma unroll
    for (int mt = 0; mt < 4; ++mt)
      af[mt] = *(const short8*)(fuse + (size_t)(m0 + mt * 16 + r) * IN_ + kcol);
    short8 bfr[4];
#pragma unroll
    for (int nt = 0; nt < 4; ++nt)
      bfr[nt] = *(const short8*)(&wlds[b][(nt * 16 + r) * WSTR + g * 8]);
#pragma unroll
    for (int mt = 0; mt < 4; ++mt)
#pragma unroll
      for (int nt = 0; nt < 4; ++nt) acc[mt][nt] = mfma16(af[mt], bfr[nt], acc[mt][nt]);
    __syncthreads();
  }
#pragma unroll
  for (int mt = 0; mt < 4; ++mt)
#pragma unroll
    for (int nt = 0; nt < 4; ++nt)
#pragma unroll
      for (int e = 0; e < 4; ++e) {
        int m = m0 + mt * 16 + g * 4 + e;
        int n = n0 + nt * 16 + r;
        part[(size_t)kz * 1048576 + (size_t)m * 2048 + n] = acc[mt][nt][e];
      }
}

// sum split-K partials + bias + relu -> X7 bf16 [512][2048]; float4 IO
__global__ void fc6_reduce(const float* __restrict__ part, const float* __restrict__ b6c,
                           const float* __restrict__ b6r, ushort* __restrict__ X7) {
  int idx4 = (blockIdx.x * 256 + threadIdx.x) * 4;  // grid 1024 -> 1,048,576 elems
  float4 s = {0.f, 0.f, 0.f, 0.f};
#pragma unroll
  for (int z = 0; z < FZ; ++z) {
    float4 v = *(const float4*)(part + (size_t)z * 1048576 + idx4);
    s.x += v.x; s.y += v.y; s.z += v.z; s.w += v.w;
  }
  int n = idx4 & 2047;
  const float* bb = (n < 1024) ? (b6c + n) : (b6r + (n - 1024));
  ushort4v o;
  o[0] = f2bf(fmaxf(s.x + bb[0], 0.f));
  o[1] = f2bf(fmaxf(s.y + bb[1], 0.f));
  o[2] = f2bf(fmaxf(s.z + bb[2], 0.f));
  o[3] = f2bf(fmaxf(s.w + bb[3], 0.f));
  *(ushort4v*)(X7 + idx4) = o;
}

// ---------------- fc7: [512][1024] x W7p[2048][1024]^T bf16 per half ------------
__global__ __launch_bounds__(128) void fc7_kernel(
    const ushort* __restrict__ X7, const ushort* __restrict__ W7p,
    const float* __restrict__ b7c, const float* __restrict__ b7r,
    float* __restrict__ out) {
  const int lane = threadIdx.x & 63, wv = threadIdx.x >> 6;
  const int r = lane & 15, g = lane >> 4;
  const int m0 = blockIdx.x * 32 + wv * 16;
  const int n0 = blockIdx.y * 32;
  const int half = (n0 >= 1024) ? 1 : 0;
  const int nn0 = n0 - half * 1024;
  const float* b7 = half ? b7r : b7c;
  f32x4 acc[2];
#pragma unroll
  for (int nt = 0; nt < 2; ++nt) acc[nt] = f32x4{0.f, 0.f, 0.f, 0.f};
  const ushort* arow = X7 + (size_t)(m0 + r) * 2048 + half * 1024;
  for (int kk = 0; kk < 1024; kk += 32) {
    short8 a = *(const short8*)(arow + kk + g * 8);
#pragma unroll
    for (int nt = 0; nt < 2; ++nt) {
      short8 bb = *(const short8*)(W7p + (size_t)(half * 1024 + nn0 + nt * 16 + r) * 1024 + kk + g * 8);
      acc[nt] = mfma16(a, bb, acc[nt]);
    }
  }
  float* obase = out + (size_t)half * 524288;
#pragma unroll
  for (int nt = 0; nt < 2; ++nt) {
#pragma unroll
    for (int e = 0; e < 4; ++e) {
      int m = m0 + g * 4 + e;
      int n = nn0 + nt * 16 + r;
      obase[(size_t)m * 1024 + n] = fmaxf(acc[nt][e] + b7[n], 0.f);
    }
  }
}

// ---------------- launch ----------------
extern "C" void kernel_launch(void* const* d_in, const int* in_sizes, int n_in,
                              void* d_out, int out_size, void* d_ws, size_t ws_size,
                              hipStream_t stream) {
  const float* x    = (const float*)d_in[0];
  const float* sup  = (const float*)d_in[1];
  const float* Wqv  = (const float*)d_in[2];
  const float* bqv  = (const float*)d_in[3];
  const float* Wqk  = (const float*)d_in[4];
  const float* bqk  = (const float*)d_in[5];
  const float* Wsv  = (const float*)d_in[6];
  const float* bsv  = (const float*)d_in[7];
  const float* Wsk  = (const float*)d_in[8];
  const float* bsk  = (const float*)d_in[9];
  const float* W6c  = (const float*)d_in[10];
  const float* b6c  = (const float*)d_in[11];
  const float* W7c  = (const float*)d_in[12];
  const float* b7c  = (const float*)d_in[13];
  const float* W6r  = (const float*)d_in[14];
  const float* b6r  = (const float*)d_in[15];
  const float* W7r  = (const float*)d_in[16];
  const float* b7r  = (const float*)d_in[17];
  float* out = (float*)d_out;

  char* base = (char*)d_ws;
  size_t off = 0;
  auto alloc = [&](size_t bytes) {
    char* p = base + off;
    off += (bytes + 255) & ~(size_t)255;
    return p;
  };
  // Region B: attn pnum bf16 NZ=8 (51.4MB) then fc6 part f32 (33.6MB), aliased
  char* regionB = alloc((size_t)NZ * M_Q * 128 * 2);
  ushort* pnum = (ushort*)regionB;
  float*  part = (float*)regionB;
  // Persistent
  ushort* W6p  = (ushort*)alloc((size_t)2048 * IN_ * 2);
  ushort* W7p  = (ushort*)alloc((size_t)2048 * 1024 * 2);
  ushort* Wq_h = (ushort*)alloc(65536 * 2);
  ushort* Ws_h = (ushort*)alloc(65536 * 2);
  float*  biasq = (float*)alloc(256 * 4);
  float*  biass = (float*)alloc(256 * 4);
  ushort* fuse = (ushort*)alloc((size_t)512 * IN_ * 2);
  ushort* qk_h = (ushort*)alloc((size_t)M_Q * 128 * 2);
  ushort* sk_h = (ushort*)alloc((size_t)M_S * 128 * 2);
  ushort* svT  = (ushort*)alloc((size_t)M_S * 128 * 2);
  float*  pden = (float*)alloc((size_t)NZ * M_Q * 4);
  ushort* X7   = (ushort*)alloc((size_t)512 * 2048 * 2);
  if (off > ws_size) return;  // insufficient scratch; validation will show poison

  // 1) conv weight pack (small)
  pack_w<<<dim3(515), dim3(256), 0, stream>>>(Wqv, Wqk, bqv, bqk, Wsv, Wsk, bsv, bsk,
                                              Wq_h, biasq, Ws_h, biass);
  // 2) convs + W6/W7 packs fused (packs stream HBM under MFMA-bound convs)
  conv_pack_kernel<<<dim3(NCONV + 2048 + 8192), dim3(256), 0, stream>>>(
      x, sup, Wq_h, Ws_h, biasq, biass, fuse, qk_h, svT, sk_h,
      W6c, W6r, W6p, W7c, W7r, W7p);
  // 3) fused attention (standalone, clean) + combine
  attn_kernel<<<dim3(196, NZ), dim3(256), 0, stream>>>(qk_h, sk_h, svT, pnum, pden);
  attn_reduce<<<dim3(3136), dim3(256), 0, stream>>>(pnum, pden, fuse);
  // 4) fc6 (512-thr blocks, K-split, XCD-local kz, W6p LDS-staged) + reduce+relu
  fc6_kernel<<<dim3(32, FZ), dim3(512), 0, stream>>>(fuse, W6p, part);
  fc6_reduce<<<dim3(1024), dim3(256), 0, stream>>>(part, b6c, b6r, X7);
  // 5) fc7 + bias + relu -> d_out (xc then xr)
  fc7_kernel<<<dim3(16, 64), dim3(128), 0, stream>>>(X7, W7p, b7c, b7r, out);
}